// Round 1
// baseline (338.097 us; speedup 1.0000x reference)
//
#include <hip/hip_runtime.h>

// Problem constants
#define BN   4
#define CIN  64
#define COUT 64
#define HH   128
#define WW   128
#define HW   16384      // 128*128
#define K2N  9
#define NOFF 18         // 2*K2

// ---------------------------------------------------------------------------
// Weight transposes (run once per launch, tiny):
//   Wt  [k2][cin][cout]  from w_deform[cout][cin][k2]   (36864 floats)
//   Wot [cin][k][c18]    from w_offset[c][cin][k]       (10368 floats)
// Contiguous-in-cout layouts let the hot kernels read weights with
// wave-uniform addresses -> scalar s_load, zero VALU/LDS cost.
// ---------------------------------------------------------------------------
__global__ __launch_bounds__(256) void transpose_weights(
    const float* __restrict__ w_def, const float* __restrict__ w_off,
    float* __restrict__ Wt, float* __restrict__ Wot) {
    int idx = blockIdx.x * 256 + threadIdx.x;
    if (idx < K2N * CIN * COUT) {
        int k2 = idx >> 12;          // / 4096
        int r = idx & 4095;
        int cin = r >> 6;
        int cout = r & 63;
        Wt[idx] = w_def[(cout * CIN + cin) * K2N + k2];
    } else {
        int d = idx - K2N * CIN * COUT;
        if (d < CIN * K2N * NOFF) {
            int cin = d / (K2N * NOFF);
            int r = d % (K2N * NOFF);
            int k = r / NOFF;
            int c = r % NOFF;
            Wot[d] = w_off[(c * CIN + cin) * K2N + k];
        }
    }
}

// ---------------------------------------------------------------------------
// Stage 1: 3x3 conv producing 18 offset channels.
// One thread per pixel, all 18 channels in registers. x neighborhood loaded
// once per cin (9 loads) and reused across the 18 couts; weights are
// wave-uniform scalar loads.
// ---------------------------------------------------------------------------
__global__ __launch_bounds__(256) void offset_conv(
    const float* __restrict__ x, const float* __restrict__ Wot,
    const float* __restrict__ boff, float* __restrict__ offs) {
    int idx = blockIdx.x * 256 + threadIdx.x;
    int b = idx >> 14;
    int hw = idx & (HW - 1);
    int h = hw >> 7;
    int w = hw & 127;

    float acc[NOFF];
#pragma unroll
    for (int c = 0; c < NOFF; c++) acc[c] = boff[c];

    const float* xb = x + ((long)b << 20);  // b * CIN * HW
    for (int cin = 0; cin < CIN; cin++) {
        const float* xp = xb + (cin << 14);
        float v[9];
#pragma unroll
        for (int kh = 0; kh < 3; kh++) {
            int y = h - 1 + kh;
            bool yok = (unsigned)y < (unsigned)HH;
            int yc = min(max(y, 0), HH - 1);
#pragma unroll
            for (int kw = 0; kw < 3; kw++) {
                int xx = w - 1 + kw;
                bool ok = yok && ((unsigned)xx < (unsigned)WW);
                float val = xp[yc * WW + min(max(xx, 0), WW - 1)];
                v[kh * 3 + kw] = ok ? val : 0.f;
            }
        }
        const float* wr = Wot + cin * (K2N * NOFF);
#pragma unroll
        for (int k = 0; k < 9; k++) {
#pragma unroll
            for (int c = 0; c < NOFF; c++) {
                acc[c] = fmaf(wr[k * NOFF + c], v[k], acc[c]);
            }
        }
    }
    float* ob = offs + (((long)b * NOFF) << 14) + hw;
#pragma unroll
    for (int c = 0; c < NOFF; c++) ob[c << 14] = acc[c];
}

// ---------------------------------------------------------------------------
// Stage 2: deformable conv. One thread per output pixel, acc[64] couts in
// registers. Per (k2): compute bilinear coords once (validity folded into the
// 4 corner weights, indices clamped — matches reference mask-multiply).
// Per cin: 4 gathers + blend -> one sampled value reused across 64 couts
// with wave-uniform (scalar-loaded) weights.
// ---------------------------------------------------------------------------
__global__ __launch_bounds__(256) void deform_conv(
    const float* __restrict__ x, const float* __restrict__ offs,
    const float* __restrict__ Wt, const float* __restrict__ bdef,
    float* __restrict__ out) {
    int idx = blockIdx.x * 256 + threadIdx.x;
    int b = idx >> 14;
    int hw = idx & (HW - 1);
    int h = hw >> 7;
    int w = hw & 127;

    float acc[COUT];
#pragma unroll
    for (int c = 0; c < COUT; c++) acc[c] = bdef[c];

    const float* xb = x + ((long)b << 20);
    const float* ob = offs + (((long)b * NOFF) << 14) + hw;

    for (int k2 = 0; k2 < K2N; k2++) {
        int kh = k2 / 3;
        int kw = k2 - kh * 3;
        float dy = ob[(2 * k2) << 14];
        float dx = ob[(2 * k2 + 1) << 14];
        float py = (float)(h - 1 + kh) + dy;
        float px = (float)(w - 1 + kw) + dx;
        float y0f = floorf(py), x0f = floorf(px);
        int y0 = (int)y0f, x0 = (int)x0f;
        float wy1 = py - y0f, wy0 = 1.f - wy1;
        float wx1 = px - x0f, wx0 = 1.f - wx1;
        int y1 = y0 + 1, x1 = x0 + 1;
        bool vy0 = (unsigned)y0 < (unsigned)HH, vy1 = (unsigned)y1 < (unsigned)HH;
        bool vx0 = (unsigned)x0 < (unsigned)WW, vx1 = (unsigned)x1 < (unsigned)WW;
        float w00 = (vy0 && vx0) ? wy0 * wx0 : 0.f;
        float w01 = (vy0 && vx1) ? wy0 * wx1 : 0.f;
        float w10 = (vy1 && vx0) ? wy1 * wx0 : 0.f;
        float w11 = (vy1 && vx1) ? wy1 * wx1 : 0.f;
        int y0c = min(max(y0, 0), HH - 1), y1c = min(max(y1, 0), HH - 1);
        int x0c = min(max(x0, 0), WW - 1), x1c = min(max(x1, 0), WW - 1);
        int i00 = y0c * WW + x0c, i01 = y0c * WW + x1c;
        int i10 = y1c * WW + x0c, i11 = y1c * WW + x1c;

        const float* wk = Wt + (k2 << 12);  // [cin][cout] slab for this k2
        for (int cin = 0; cin < CIN; cin++) {
            const float* xp = xb + (cin << 14);
            float s = w00 * xp[i00] + w01 * xp[i01] + w10 * xp[i10] + w11 * xp[i11];
            const float* wr = wk + (cin << 6);
#pragma unroll
            for (int c = 0; c < COUT; c++) {
                acc[c] = fmaf(wr[c], s, acc[c]);
            }
        }
    }

    float* op = out + (((long)b * COUT) << 14) + hw;
#pragma unroll
    for (int c = 0; c < COUT; c++) op[c << 14] = acc[c];
}

// ---------------------------------------------------------------------------
extern "C" void kernel_launch(void* const* d_in, const int* in_sizes, int n_in,
                              void* d_out, int out_size, void* d_ws, size_t ws_size,
                              hipStream_t stream) {
    const float* x     = (const float*)d_in[0];  // (4,64,128,128)
    const float* w_off = (const float*)d_in[1];  // (18,64,3,3)
    const float* b_off = (const float*)d_in[2];  // (18,)
    const float* w_def = (const float*)d_in[3];  // (64,64,3,3)
    const float* b_def = (const float*)d_in[4];  // (64,)
    float* out = (float*)d_out;                  // (4,64,128,128)

    // Workspace layout (floats): offsets | Wt | Wot  (~4.9 MB total)
    float* offs = (float*)d_ws;                       // 4*18*16384 = 1179648
    float* Wt   = offs + (long)BN * NOFF * HW;        // 36864
    float* Wot  = Wt + K2N * CIN * COUT;              // 10368

    const int n_t = K2N * CIN * COUT + CIN * K2N * NOFF;  // 47232
    hipLaunchKernelGGL(transpose_weights, dim3((n_t + 255) / 256), dim3(256), 0, stream,
                       w_def, w_off, Wt, Wot);

    const int n_pix = BN * HW;  // 65536
    hipLaunchKernelGGL(offset_conv, dim3(n_pix / 256), dim3(256), 0, stream,
                       x, Wot, b_off, offs);
    hipLaunchKernelGGL(deform_conv, dim3(n_pix / 256), dim3(256), 0, stream,
                       x, offs, Wt, b_def, out);
}